// Round 8
// baseline (178.642 us; speedup 1.0000x reference)
//
#include <hip/hip_runtime.h>
#include <hip/hip_bf16.h>

typedef unsigned short u16;
typedef unsigned int u32;
typedef __attribute__((ext_vector_type(8))) short bf16x8;   // 8 bf16 (4 VGPRs)
typedef __attribute__((ext_vector_type(4))) short s16x4;
typedef __attribute__((ext_vector_type(4))) float f32x4;

#define NN 4096

__device__ __forceinline__ u16 f2bf(float f) {
    union { float f; u32 u; } v; v.f = f;
    u32 r = v.u + 0x7fffu + ((v.u >> 16) & 1u);   // RNE (inputs finite)
    return (u16)(r >> 16);
}

// ---------------- K1: deg = rowsum(A); inv_d = 1/(deg+1) ----------------
__global__ void rowsum_kernel(const float* __restrict__ A, float* __restrict__ invd) {
    const int row = blockIdx.x;
    const float4* a4 = reinterpret_cast<const float4*>(A + (size_t)row * NN);
    float s = 0.f;
    #pragma unroll
    for (int i = 0; i < 4; ++i) {
        float4 v = a4[threadIdx.x + i * 256];
        s += v.x + v.y + v.z + v.w;
    }
    #pragma unroll
    for (int off = 32; off > 0; off >>= 1) s += __shfl_down(s, off, 64);
    __shared__ float ws[4];
    if ((threadIdx.x & 63) == 0) ws[threadIdx.x >> 6] = s;
    __syncthreads();
    if (threadIdx.x == 0) {
        float t = ws[0] + ws[1] + ws[2] + ws[3];
        invd[row] = 1.0f / (t + 1.0f);
    }
}

// ------- K2: temp = 0.5*h + 0.5*(A + I)*inv_d[col]  -> bf16 [M][K] -------
__global__ void make_temp_kernel(const float* __restrict__ A, const float* __restrict__ h,
                                 const float* __restrict__ invd, u16* __restrict__ T) {
    const size_t g = ((size_t)blockIdx.x * 256 + threadIdx.x) * 8;
    const int row = (int)(g >> 12);
    const int col = (int)(g & 4095);
    const float4* a4 = reinterpret_cast<const float4*>(A + g);
    const float4* h4 = reinterpret_cast<const float4*>(h + g);
    const float4* d4 = reinterpret_cast<const float4*>(invd + col);
    float4 a0 = a4[0], a1 = a4[1];
    float4 h0 = h4[0], h1 = h4[1];
    float4 dd0 = d4[0], dd1 = d4[1];
    float av[8] = {a0.x,a0.y,a0.z,a0.w,a1.x,a1.y,a1.z,a1.w};
    float hv[8] = {h0.x,h0.y,h0.z,h0.w,h1.x,h1.y,h1.z,h1.w};
    float dv[8] = {dd0.x,dd0.y,dd0.z,dd0.w,dd1.x,dd1.y,dd1.z,dd1.w};
    bf16x8 o;
    #pragma unroll
    for (int j = 0; j < 8; ++j) {
        float aa = av[j] + ((col + j == row) ? 1.0f : 0.0f);
        float t = 0.5f * hv[j] + 0.5f * aa * dv[j];
        o[j] = (short)f2bf(t);
    }
    *reinterpret_cast<bf16x8*>(T + g) = o;
}

// --------- K3: Wt[n][k] = bf16(W[k][n])  (LDS 64x64 tile transpose) ---------
__global__ void transposeW_kernel(const float* __restrict__ W, u16* __restrict__ Wt) {
    __shared__ float tile[64][65];
    const int nt = blockIdx.x & 63;
    const int kt = blockIdx.x >> 6;
    const int k0 = kt * 64, n0 = nt * 64;
    const int tr = threadIdx.x >> 4;          // 0..15
    const int tc = (threadIdx.x & 15) * 4;    // 0..60
    #pragma unroll
    for (int rr = 0; rr < 64; rr += 16) {
        float4 v = *reinterpret_cast<const float4*>(&W[(size_t)(k0 + tr + rr) * NN + n0 + tc]);
        tile[tr + rr][tc + 0] = v.x;
        tile[tr + rr][tc + 1] = v.y;
        tile[tr + rr][tc + 2] = v.z;
        tile[tr + rr][tc + 3] = v.w;
    }
    __syncthreads();
    #pragma unroll
    for (int rr = 0; rr < 64; rr += 16) {
        const int n = tr + rr;
        s16x4 o;
        #pragma unroll
        for (int j = 0; j < 4; ++j) o[j] = (short)f2bf(tile[tc + j][n]);
        *reinterpret_cast<s16x4*>(&Wt[(size_t)(n0 + n) * NN + k0 + tc]) = o;
    }
}

// ============ K4: C[M][N] = temp[M][K] @ Wt[N][K]^T (bf16 MFMA) ============
// R8: role-split ping-pong. 256x256 tile, BK=32, 3 LDS bufs (96KB), 8 waves.
// Each K-step = 2 windows: [role0 reads(s) | role1 MFMA(s-1)] barrier
// [role0 MFMA(s) | role1 reads(s)] vmcnt barrier. On each SIMD one wave
// reads while the other MFMAs -> DS pipe and matrix pipes overlap instead
// of alternating (the R2-R7 lockstep wall). Stage tile s+2 at even window
// (all waves, own lane slices), vmcnt(4) at odd-window end (0 at s=126).

#define GLD16(g, l) __builtin_amdgcn_global_load_lds( \
    (const __attribute__((address_space(1))) void*)(g), \
    (__attribute__((address_space(3))) void*)(l), 16, 0, 0)

__global__ __launch_bounds__(512, 2) void gemm_kernel(
    const u16* __restrict__ Atl,   // [M][K] bf16 (temp)
    const u16* __restrict__ Btl,   // [N][K] bf16 (Wt)
    float* __restrict__ C)         // [M][N] f32
{
    __shared__ u16 S[3][2][8192];  // [buf][A=0/B=1][256 rows x 32 k] = 96 KiB

    const int tid  = threadIdx.x;
    const int wid  = tid >> 6;     // 0..7
    const int lane = tid & 63;
    const int llo  = lane & 15;
    const int lhi  = lane >> 4;    // 0..3
    const int wr   = wid >> 2;     // 0..1  (M half) == ROLE
    const int wc   = wid & 3;      // 0..3  (N quarter)
    const bool role1 = (wr != 0);  // waves 4..7: read odd, MFMA even

    // XCD swizzle (grid=256, 256%8==0 -> bijective)
    const int swz = ((int)blockIdx.x & 7) * 32 + ((int)blockIdx.x >> 3);
    const int bm = swz >> 4, bn = swz & 15;
    const int tileRow = bm * 256, tileCol = bn * 256;

    // ---- staging (R2-proven, 0 conflicts): linear dest, inv-swizzled src ----
    const int r0 = tid >> 2;                                 // 0..127
    const int kc = (((tid & 3) ^ ((r0 >> 1) & 3)) << 3);
    const size_t R128 = (size_t)128 * NN;
    const u16* gA0 = Atl + (size_t)(tileRow + r0) * NN + kc;
    const u16* gA1 = gA0 + R128;
    const u16* gB0 = Btl + (size_t)(tileCol + r0) * NN + kc;
    const u16* gB1 = gB0 + R128;

    #define STAGE(WB, KOFF) do { \
        GLD16(gA0 + (KOFF), &S[WB][0][tid * 8]); \
        GLD16(gA1 + (KOFF), &S[WB][0][4096 + tid * 8]); \
        GLD16(gB0 + (KOFF), &S[WB][1][tid * 8]); \
        GLD16(gB1 + (KOFF), &S[WB][1][4096 + tid * 8]); } while (0)

    // ---- swizzled read offsets (R2-proven) ----
    int offA[8], offB[4];
    #pragma unroll
    for (int m = 0; m < 8; ++m) {
        const int row = wr * 128 + m * 16 + llo;
        offA[m] = row * 32 + ((lhi ^ ((row >> 1) & 3)) << 3);
    }
    #pragma unroll
    for (int n = 0; n < 4; ++n) {
        const int row = wc * 64 + n * 16 + llo;
        offB[n] = row * 32 + ((lhi ^ ((row >> 1) & 3)) << 3);
    }

    f32x4 acc[8][4];
    #pragma unroll
    for (int m = 0; m < 8; ++m)
        #pragma unroll
        for (int n = 0; n < 4; ++n)
            acc[m][n] = (f32x4){0.f, 0.f, 0.f, 0.f};

    bf16x8 af[8], bv[4];   // single frag set per wave (read window -> MFMA window)

    #define READF(BI) do { \
        const u16* sA = &S[BI][0][0]; \
        const u16* sB = &S[BI][1][0]; \
        _Pragma("unroll") \
        for (int m = 0; m < 8; ++m) af[m] = *reinterpret_cast<const bf16x8*>(sA + offA[m]); \
        _Pragma("unroll") \
        for (int n = 0; n < 4; ++n) bv[n] = *reinterpret_cast<const bf16x8*>(sB + offB[n]); \
    } while (0)

    #define MFMACL() do { \
        __builtin_amdgcn_s_setprio(1); \
        _Pragma("unroll") \
        for (int m = 0; m < 8; ++m) \
            _Pragma("unroll") \
            for (int n = 0; n < 4; ++n) \
                acc[m][n] = __builtin_amdgcn_mfma_f32_16x16x32_bf16(af[m], bv[n], acc[m][n], 0, 0, 0); \
        __builtin_amdgcn_s_setprio(0); \
    } while (0)

    // ---- prologue: stage tiles 0,1 into bufs 0,1 ----
    STAGE(0, 0);
    STAGE(1, 32);
    asm volatile("s_waitcnt vmcnt(4)" ::: "memory");   // tile 0 landed
    __builtin_amdgcn_s_barrier();
    asm volatile("" ::: "memory");

    int bi = 0;   // buf holding tile s
    int bw = 2;   // buf for tile s+2

    #pragma unroll 1
    for (int s = 0; s < 128; ++s) {
        // ===== EVEN window: stage(s+2) | role0 reads(s), role1 MFMA(s-1) =====
        if (s <= 125) STAGE(bw, (s + 2) * 32);
        __builtin_amdgcn_sched_barrier(0);
        if (!role1) {
            READF(bi);
        } else if (s > 0) {
            MFMACL();
        }
        __builtin_amdgcn_s_barrier();
        asm volatile("" ::: "memory");

        // ===== ODD window: role0 MFMA(s), role1 reads(s) =====
        if (!role1) {
            MFMACL();
        } else {
            READF(bi);
        }
        // enforce landing: tiles <= s+1 must be in LDS before windows of s+1.
        if (s <= 125)      asm volatile("s_waitcnt vmcnt(4)" ::: "memory");
        else if (s == 126) asm volatile("s_waitcnt vmcnt(0)" ::: "memory");
        __builtin_amdgcn_s_barrier();
        asm volatile("" ::: "memory");

        bi = (bi == 2) ? 0 : bi + 1;
        bw = (bw == 2) ? 0 : bw + 1;
    }
    // role1 waves owe the last MFMA (frags of tile 127 read at the final odd window)
    if (role1) MFMACL();
    #undef STAGE
    #undef READF
    #undef MFMACL

    // ---- epilogue: C/D layout col=lane&15, row=(lane>>4)*4+reg ----
    #pragma unroll
    for (int m = 0; m < 8; ++m) {
        #pragma unroll
        for (int n = 0; n < 4; ++n) {
            const size_t rbase = (size_t)(tileRow + wr * 128 + m * 16 + lhi * 4) * NN
                               + tileCol + wc * 64 + n * 16 + llo;
            #pragma unroll
            for (int j = 0; j < 4; ++j)
                C[rbase + (size_t)j * NN] = acc[m][n][j];
        }
    }
}

// ---------------------------------------------------------------------------
extern "C" void kernel_launch(void* const* d_in, const int* in_sizes, int n_in,
                              void* d_out, int out_size, void* d_ws, size_t ws_size,
                              hipStream_t stream) {
    const float* A = (const float*)d_in[0];
    const float* h = (const float*)d_in[1];
    const float* W = (const float*)d_in[2];
    float* out = (float*)d_out;

    // workspace layout: inv_d (16KB) | temp bf16 (32MB) | Wt bf16 (32MB)
    float* invd = (float*)d_ws;
    u16* temp = (u16*)((char*)d_ws + 16384);
    u16* wt   = temp + (size_t)NN * NN;

    rowsum_kernel<<<NN, 256, 0, stream>>>(A, invd);
    make_temp_kernel<<<(NN * (size_t)NN) / (256 * 8), 256, 0, stream>>>(A, h, invd, temp);
    transposeW_kernel<<<(NN / 64) * (NN / 64), 256, 0, stream>>>(W, wt);
    gemm_kernel<<<256, 512, 0, stream>>>(temp, wt, out);
}